// Round 15
// baseline (8001.328 us; speedup 1.0000x reference)
//
#include <hip/hip_runtime.h>
#include <math.h>
#include <stdint.h>

#define BB 32
#define DD 64
#define HH 8
#define NNN 4096
#define LL 12
#define PP (NNN * LL)            // 49152 positions per (b, channel)

// pass_a geometry (R10 form): 512-thread blocks, 64-pos tiles
#define NTILES_A 24
#define CHUNK_A (64 * NTILES_A)  // 1536
#define NCHUNK_A (PP / CHUNK_A)  // 32  -> 1024 blocks

// pass_b geometry: 256-thread blocks, 64-pos tiles, 2 half-grid dispatches
#define NTILES_B 12
#define CHUNK_B (64 * NTILES_B)  // 768
#define NCHUNK_B (PP / CHUNK_B)  // 64 chunks total; 32 per dispatch

#define VSTRIDE 68               // pass_a v_tile row stride (16B-aligned)
#define SCALE 0.35355339059327373f

typedef const __attribute__((address_space(1))) uint32_t gu32;
typedef __attribute__((address_space(3))) uint32_t lu32;

// global->LDS DMA, 16B per lane, zero VGPR cost.
__device__ __forceinline__ void dma16(const float* src, float* dst) {
    __builtin_amdgcn_global_load_lds((gu32*)src, (lu32*)dst, 16, 0, 0);
}

// ---------------------------------------------------------------------------
// prep_all: fused {kv zero, weight transpose, key-softmax table, wb table}.
// One 3072x256 launch replaces memset + 3 prep kernels (saves ~3 launches;
// wb path vectorized to float4).  ksm/wb sections skipped when null.
// ---------------------------------------------------------------------------
__global__ void prep_all(const float* __restrict__ wq, const float* __restrict__ wv,
                         const float* __restrict__ wc, const float* __restrict__ mem,
                         const float* __restrict__ wgt, const float* __restrict__ bsa,
                         float* __restrict__ wt, float* __restrict__ ksm,
                         float* __restrict__ wb, float* __restrict__ kvz)
{
    const int t = blockIdx.x * 256 + threadIdx.x;  // 0..786431

    // kv zero: 196608 floats = 49152 float4
    if (t < 49152) ((float4*)kvz)[t] = make_float4(0.f, 0.f, 0.f, 0.f);

    // weight transpose: 4096 jobs (i = o*64 + c)
    if (t < 4096) {
        const int o = t >> 6, c = t & 63;
        wt[c * 64 + o]        = wq[t];
        wt[4096 + c * 64 + o] = wv[t];
        wt[8192 + c * 64 + o] = wc[t];
    }

    // key-softmax table: 393216 (p,h) jobs; ksm[p][h][x], p = n*12+l
    if (ksm && t < 393216) {
        const int p = t >> 3, h = t & 7;
        const int n = p / 12, l = p - n * 12;
        const float4* mp = (const float4*)(mem + (((size_t)(h * 12 + l) * NNN + n) << 3));
        float4 a0 = mp[0], a1 = mp[1];
        float v0 = a0.x * SCALE, v1 = a0.y * SCALE, v2 = a0.z * SCALE, v3 = a0.w * SCALE;
        float v4 = a1.x * SCALE, v5 = a1.y * SCALE, v6 = a1.z * SCALE, v7 = a1.w * SCALE;
        float m = fmaxf(fmaxf(fmaxf(v0, v1), fmaxf(v2, v3)),
                        fmaxf(fmaxf(v4, v5), fmaxf(v6, v7)));
        float e0 = __expf(v0 - m), e1 = __expf(v1 - m), e2 = __expf(v2 - m), e3 = __expf(v3 - m);
        float e4 = __expf(v4 - m), e5 = __expf(v5 - m), e6 = __expf(v6 - m), e7 = __expf(v7 - m);
        float inv = 1.0f / (e0 + e1 + e2 + e3 + e4 + e5 + e6 + e7);
        float4* op = (float4*)(ksm + ((size_t)t << 3));
        op[0] = make_float4(e0 * inv, e1 * inv, e2 * inv, e3 * inv);
        op[1] = make_float4(e4 * inv, e5 * inv, e6 * inv, e7 * inv);
    }

    // wb table: 3145728 entries, 4 per thread, float4 in/out
    if (wb) {
        const size_t i0 = (size_t)t << 2;
        float4 wg = *(const float4*)(wgt + i0);
        float4 bs = *(const float4*)(bsa + i0);
        float4* op = (float4*)(wb + (i0 << 1));
        op[0] = make_float4(wg.x + 1.f, bs.x, wg.y + 1.f, bs.y);
        op[1] = make_float4(wg.z + 1.f, bs.z, wg.w + 1.f, bs.w);
    }
}

// ---------------------------------------------------------------------------
// Pass A: R10's measured-best form, verbatim (<= 392 us, proven R14).
// ---------------------------------------------------------------------------
__global__ __launch_bounds__(512, 4)
void pass_a(const float* __restrict__ x, const float* __restrict__ wvt,
            const float* __restrict__ bv, const float* __restrict__ mem,
            const float* __restrict__ ksm,  // p-major key-softmax, or null
            float* __restrict__ kv)
{
    __shared__ float xb0[64 * 64];          // linear (DMA target)
    __shared__ float xb1[64 * 64];          // linear (DMA target)
    __shared__ float ksl[64 * 64];          // linear [pos][h*8+x]
    __shared__ float v_tile[64 * VSTRIDE];  // [p][slot], slot swizzled

    const int t = threadIdx.x;
    const int b = blockIdx.y;
    const int chunk0 = blockIdx.x * CHUNK_A;

    const int p1 = t & 63;
    const int og = t >> 6;           // wave-uniform
    const int o0 = og << 3;
    const int o0u = __builtin_amdgcn_readfirstlane(o0);
    const float* __restrict__ wvu = wvt + o0u;

    float bvl[8];
#pragma unroll
    for (int j = 0; j < 8; j++) bvl[j] = bv[o0u + j];  // scalar path

    // DMA lane mapping
    const int wid = t >> 6;          // wave id 0..7
    const int ln  = t & 63;
    const int g_r = ln >> 4;
    const int g_c4 = (ln & 15) << 2;

    // stage-2 mapping
    const int h2 = (t >> 3) & 7;
    const int x2 = t & 7;
    const int l0 = t >> 6;
    const int l1 = 8 + (t >> 6);
    const bool has2 = (t < 256);

    float acc[2][8];
#pragma unroll
    for (int q = 0; q < 2; q++)
#pragma unroll
        for (int y = 0; y < 8; y++) acc[q][y] = 0.f;

    const float* xb = x + (size_t)(b * 64) * PP;

    auto issue_x = [&](float* dst, int pn) {
        const int r0 = wid << 3;
        dma16(xb + (size_t)(r0 + g_r) * PP + pn + g_c4, dst + (r0 << 6));
        dma16(xb + (size_t)(r0 + 4 + g_r) * PP + pn + g_c4, dst + ((r0 + 4) << 6));
    };
    auto issue_ks = [&](int pn) {
        const int fo = wid << 9;
        const float* s0 = ksm + (((size_t)pn) << 6) + fo + (ln << 2);
        dma16(s0, ksl + fo);
        dma16(s0 + 256, ksl + fo + 256);
    };
    auto fallback_ks = [&](int pbase) {
        int pos = t >> 3, h = t & 7;
        int pg = pbase + pos;
        int n = pg / 12;
        int l = pg - n * 12;
        const float4* mp = (const float4*)(mem + (((size_t)(h * 12 + l) * NNN + n) << 3));
        float4 a0 = mp[0], a1 = mp[1];
        float v0 = a0.x * SCALE, v1 = a0.y * SCALE, v2 = a0.z * SCALE, v3 = a0.w * SCALE;
        float v4 = a1.x * SCALE, v5 = a1.y * SCALE, v6 = a1.z * SCALE, v7 = a1.w * SCALE;
        float m = fmaxf(fmaxf(fmaxf(v0, v1), fmaxf(v2, v3)),
                        fmaxf(fmaxf(v4, v5), fmaxf(v6, v7)));
        float e0 = __expf(v0 - m), e1 = __expf(v1 - m), e2 = __expf(v2 - m), e3 = __expf(v3 - m);
        float e4 = __expf(v4 - m), e5 = __expf(v5 - m), e6 = __expf(v6 - m), e7 = __expf(v7 - m);
        float inv = 1.0f / (e0 + e1 + e2 + e3 + e4 + e5 + e6 + e7);
        float4* kp = (float4*)(ksl + (pos << 6) + (h << 3));
        kp[0] = make_float4(e0 * inv, e1 * inv, e2 * inv, e3 * inv);
        kp[1] = make_float4(e4 * inv, e5 * inv, e6 * inv, e7 * inv);
    };

    issue_x(xb0, chunk0);
    if (ksm) issue_ks(chunk0); else fallback_ks(chunk0);
    __syncthreads();

    for (int tile = 0; tile < NTILES_A; tile++) {
        const int pbase = chunk0 + tile * 64;
        float* bufA = (tile & 1) ? xb1 : xb0;
        float* bufB = (tile & 1) ? xb0 : xb1;
        const bool more = (tile + 1) < NTILES_A;

        if (more) issue_x(bufB, pbase + 64);

        float va[8];
#pragma unroll
        for (int j = 0; j < 8; j++) va[j] = 0.f;
        for (int c = 0; c < 64; c += 4) {
            float xs0 = bufA[(c << 6) + p1];
            float xs1 = bufA[((c + 1) << 6) + p1];
            float xs2 = bufA[((c + 2) << 6) + p1];
            float xs3 = bufA[((c + 3) << 6) + p1];
            const float* w0 = wvu + c * 64;
#pragma unroll
            for (int j = 0; j < 8; j++) {
                va[j] += w0[j] * xs0;
                va[j] += w0[64 + j] * xs1;
                va[j] += w0[128 + j] * xs2;
                va[j] += w0[192 + j] * xs3;
            }
        }
        {
            const int slot = ((og ^ (p1 >> 3)) & 7) << 3;
            float4* vt4 = (float4*)(v_tile + p1 * VSTRIDE + slot);
            float4 w;
            w.x = fmaxf(va[0] + bvl[0], 0.f);
            w.y = fmaxf(va[1] + bvl[1], 0.f);
            w.z = fmaxf(va[2] + bvl[2], 0.f);
            w.w = fmaxf(va[3] + bvl[3], 0.f);
            vt4[0] = w;
            w.x = fmaxf(va[4] + bvl[4], 0.f);
            w.y = fmaxf(va[5] + bvl[5], 0.f);
            w.z = fmaxf(va[6] + bvl[6], 0.f);
            w.w = fmaxf(va[7] + bvl[7], 0.f);
            vt4[1] = w;
        }
        __syncthreads();  // A

        const int r = pbase % 12;
        {
            int s = l0 - r;
            if (s < 0) s += 12;
            for (int p = s; p < 64; p += 12) {
                float ksv = ksl[(p << 6) + (h2 << 3) + x2];
                const int slot = ((h2 ^ (p >> 3)) & 7) << 3;
                const float4* vp = (const float4*)(v_tile + p * VSTRIDE + slot);
                float4 u0 = vp[0], u1 = vp[1];
                acc[0][0] += ksv * u0.x; acc[0][1] += ksv * u0.y;
                acc[0][2] += ksv * u0.z; acc[0][3] += ksv * u0.w;
                acc[0][4] += ksv * u1.x; acc[0][5] += ksv * u1.y;
                acc[0][6] += ksv * u1.z; acc[0][7] += ksv * u1.w;
            }
        }
        if (has2) {
            int s = l1 - r;
            if (s < 0) s += 12;
            for (int p = s; p < 64; p += 12) {
                float ksv = ksl[(p << 6) + (h2 << 3) + x2];
                const int slot = ((h2 ^ (p >> 3)) & 7) << 3;
                const float4* vp = (const float4*)(v_tile + p * VSTRIDE + slot);
                float4 u0 = vp[0], u1 = vp[1];
                acc[1][0] += ksv * u0.x; acc[1][1] += ksv * u0.y;
                acc[1][2] += ksv * u0.z; acc[1][3] += ksv * u0.w;
                acc[1][4] += ksv * u1.x; acc[1][5] += ksv * u1.y;
                acc[1][6] += ksv * u1.z; acc[1][7] += ksv * u1.w;
            }
        }
        __syncthreads();  // B

        if (more) { if (ksm) issue_ks(pbase + 64); else fallback_ks(pbase + 64); }
    }

    {
        float* kvp = kv + (((size_t)((b * 12 + l0) * 8 + h2)) << 6) + (x2 << 3);
#pragma unroll
        for (int y = 0; y < 8; y++) atomicAdd(kvp + y, acc[0][y]);
    }
    if (has2) {
        float* kvp = kv + (((size_t)((b * 12 + l1) * 8 + h2)) << 6) + (x2 << 3);
#pragma unroll
        for (int y = 0; y < 8; y++) atomicAdd(kvp + y, acc[1][y]);
    }
}

// FMA group: 4 channels (X0..X3 at weight rows Q/V) into qa/va[16]
#define CONV_STEP(X0, X1, X2, X3, Q, V)                                  \
    _Pragma("unroll")                                                    \
    for (int j = 0; j < 16; j++) {                                       \
        qa[j] += (Q)[j] * (X0);        va[j] += (V)[j] * (X0);           \
        qa[j] += (Q)[64 + j] * (X1);   va[j] += (V)[64 + j] * (X1);      \
        qa[j] += (Q)[128 + j] * (X2);  va[j] += (V)[128 + j] * (X2);     \
        qa[j] += (Q)[192 + j] * (X3);  va[j] += (V)[192 + j] * (X3);     \
    }

// ---------------------------------------------------------------------------
// Pass B (R15): R8 structure with (a) __launch_bounds__(256,3) -> 85-VGPR
// budget (R12 measured cap) and (b) 2-deep software-pipelined conv loads:
// group k+1's 4 strided x loads are issued BEFORE group k's 128 FMAs, so
// each group's ~500-cyc HBM/L2 latency hides under the previous group's
// compute instead of serializing (the 46% stall isolated in R8/R14).
// Only +4 live VGPRs -- impossible at the (256,4)=64 cap, fits at 85.
// Trade: 4 -> 3 blocks/CU (16 -> 12 waves).  Spill tripwire: FETCH >> 300MB.
// ---------------------------------------------------------------------------
__global__ __launch_bounds__(256, 3)
void pass_b(const float* __restrict__ x, const float* __restrict__ wqt,
            const float* __restrict__ wvt, const float* __restrict__ wct,
            const float* __restrict__ bq, const float* __restrict__ bv,
            const float* __restrict__ bc, const float* __restrict__ kv,
            const float* __restrict__ wgt, const float* __restrict__ bsa,
            const float* __restrict__ wb,   // fused pairs, or null
            float* __restrict__ out, int chunk_base)
{
    __shared__ float kv_lds[12 * 512];  // [l][h][x^(l&3)][y], 24 KB
    __shared__ float y_tile[64 * 64];   // [c][p], 16 KB

    const int t = threadIdx.x;
    const int b = blockIdx.y;
    const int chunk0 = (chunk_base + blockIdx.x) * CHUNK_B;

    const int p1 = t & 63;
    const int og = t >> 6;
    const int o0 = og << 4;
    const int o0u = __builtin_amdgcn_readfirstlane(o0);
    const float* __restrict__ wqu = wqt + o0u;
    const float* __restrict__ wvu = wvt + o0u;
    const float* __restrict__ wcu = wct + o0u;

    // stage this batch's kv slice once, bank-swizzled
    {
        const float* kvb = kv + (size_t)b * 6144;
        for (int i = t; i < 6144; i += 256) {
            const int l = i >> 9;
            const int h = (i >> 6) & 7;
            const int xx = (i >> 3) & 7;
            const int y = i & 7;
            kv_lds[(l << 9) + (h << 6) + ((xx ^ (l & 3)) << 3) + y] = kvb[i];
        }
    }

    float bql[16], bvl[16], bcl[16];
#pragma unroll
    for (int j = 0; j < 16; j++) {
        bql[j] = bq[o0 + j];
        bvl[j] = bv[o0 + j];
        bcl[j] = bc[o0 + j];
    }

    const float* xb = x + (size_t)(b * 64) * PP;
    float* ob = out + (size_t)(b * 64) * PP;

    __syncthreads();

    for (int tile_i = 0; tile_i < NTILES_B; tile_i++) {
        const int pbase = chunk0 + tile_i * 64;
        const int pg = pbase + p1;
        const int l = pg % 12;

        // ---- q and v convs: strided global x, 2-deep pipelined load groups
        float qa[16], va[16];
#pragma unroll
        for (int j = 0; j < 16; j++) { qa[j] = 0.f; va[j] = 0.f; }
        const float* xp = xb + pg;

        float a0 = xp[0];
        float a1 = xp[(size_t)1 * PP];
        float a2 = xp[(size_t)2 * PP];
        float a3 = xp[(size_t)3 * PP];
        float b0, b1, b2, b3;
#pragma unroll
        for (int c = 0; c < 64; c += 8) {
            // issue group c+4 before consuming group c
            b0 = xp[(size_t)(c + 4) * PP];
            b1 = xp[(size_t)(c + 5) * PP];
            b2 = xp[(size_t)(c + 6) * PP];
            b3 = xp[(size_t)(c + 7) * PP];
            CONV_STEP(a0, a1, a2, a3, wqu + c * 64, wvu + c * 64);
            // issue group c+8 before consuming group c+4
            if (c + 8 < 64) {
                a0 = xp[(size_t)(c + 8) * PP];
                a1 = xp[(size_t)(c + 9) * PP];
                a2 = xp[(size_t)(c + 10) * PP];
                a3 = xp[(size_t)(c + 11) * PP];
            }
            CONV_STEP(b0, b1, b2, b3, wqu + (c + 4) * 64, wvu + (c + 4) * 64);
        }
#pragma unroll
        for (int j = 0; j < 16; j++) {
            qa[j] = fmaxf(qa[j] + bql[j], 0.f) * SCALE;
            va[j] = fmaxf(va[j] + bvl[j], 0.f);
        }

        // ---- softmax over DK=8 per head (2 heads/thread, in-register)
#pragma unroll
        for (int hh = 0; hh < 2; hh++) {
            float* qh = qa + hh * 8;
            float m = fmaxf(fmaxf(fmaxf(qh[0], qh[1]), fmaxf(qh[2], qh[3])),
                            fmaxf(fmaxf(qh[4], qh[5]), fmaxf(qh[6], qh[7])));
            float s = 0.f;
#pragma unroll
            for (int xk = 0; xk < 8; xk++) { qh[xk] = __expf(qh[xk] - m); s += qh[xk]; }
            float inv = 1.0f / s;
#pragma unroll
            for (int xk = 0; xk < 8; xk++) qh[xk] *= inv;
        }

        // ---- attn: y = q_sm @ kv + v   (kv from swizzled LDS)
        const int lsw = l & 3;
#pragma unroll
        for (int hh = 0; hh < 2; hh++) {
            const int h = og * 2 + hh;
            const float* kvp = kv_lds + (l << 9) + (h << 6);
            float yv[8];
#pragma unroll
            for (int y = 0; y < 8; y++) yv[y] = va[hh * 8 + y];
#pragma unroll
            for (int xk = 0; xk < 8; xk++) {
                float qv = qa[hh * 8 + xk];
                const float4* kp = (const float4*)(kvp + ((xk ^ lsw) << 3));
                float4 k0 = kp[0], k1 = kp[1];
                yv[0] += qv * k0.x; yv[1] += qv * k0.y;
                yv[2] += qv * k0.z; yv[3] += qv * k0.w;
                yv[4] += qv * k1.x; yv[5] += qv * k1.y;
                yv[6] += qv * k1.z; yv[7] += qv * k1.w;
            }
#pragma unroll
            for (int y = 0; y < 8; y++)
                y_tile[((o0 + hh * 8 + y) << 6) + p1] = yv[y];
        }
        __syncthreads();

        // ---- output conv + epilogue
        float ca[16];
#pragma unroll
        for (int j = 0; j < 16; j++) ca[j] = 0.f;
        for (int c = 0; c < 64; c += 4) {
            float y0 = y_tile[(c << 6) + p1];
            float y1 = y_tile[((c + 1) << 6) + p1];
            float y2 = y_tile[((c + 2) << 6) + p1];
            float y3 = y_tile[((c + 3) << 6) + p1];
            const float* w0 = wcu + c * 64;
#pragma unroll
            for (int j = 0; j < 16; j++) {
                ca[j] += w0[j] * y0;
                ca[j] += w0[64 + j] * y1;
                ca[j] += w0[128 + j] * y2;
                ca[j] += w0[192 + j] * y3;
            }
        }
        if (wb) {
#pragma unroll
            for (int j = 0; j < 16; j++) {
                float yc = fmaxf(ca[j] + bcl[j], 0.f);
                size_t oi = (size_t)(o0 + j) * PP + pg;
                float2 w2 = *(const float2*)(wb + oi * 2);
                ob[oi] = yc * w2.x + w2.y;
            }
        } else {
#pragma unroll
            for (int j = 0; j < 16; j++) {
                float yc = fmaxf(ca[j] + bcl[j], 0.f);
                size_t oi = (size_t)(o0 + j) * PP + pg;
                ob[oi] = yc * (wgt[oi] + 1.0f) + bsa[oi];
            }
        }
        __syncthreads();  // y reads done before next tile's y writes
    }
}

extern "C" void kernel_launch(void* const* d_in, const int* in_sizes, int n_in,
                              void* d_out, int out_size, void* d_ws, size_t ws_size,
                              hipStream_t stream) {
    const float* x   = (const float*)d_in[0];
    const float* wq  = (const float*)d_in[1];
    const float* bq  = (const float*)d_in[2];
    const float* wv  = (const float*)d_in[3];
    const float* bv  = (const float*)d_in[4];
    const float* wc  = (const float*)d_in[5];
    const float* bc  = (const float*)d_in[6];
    const float* mem = (const float*)d_in[7];
    const float* wgt = (const float*)d_in[8];
    const float* bsa = (const float*)d_in[9];
    // d_in[10], d_in[11] (nv1, nv2) are mathematically dead:
    // row-sums of a softmax over its own axis are exactly 1 -> attn_dyn = v5.
    float* outp = (float*)d_out;

    const size_t kv_floats  = (size_t)BB * LL * HH * 64;   // 196608
    const size_t wt_floats  = 3 * 4096;                    // 12288
    const size_t ksm_floats = (size_t)PP * 64;             // 3145728 (12.6 MB)
    const size_t wb_floats  = (size_t)PP * 64 * 2;         // 6291456 (25.2 MB)

    float* kvw = (float*)d_ws;
    float* wt  = kvw + kv_floats;
    float* ksm = wt + wt_floats;
    float* wb  = ksm + ksm_floats;
    const bool have_ksm =
        ws_size >= (kv_floats + wt_floats + ksm_floats) * sizeof(float);
    const bool have_wb =
        ws_size >= (kv_floats + wt_floats + ksm_floats + wb_floats) * sizeof(float);

    // fused prep: kv zero + weight transpose + ksm table + wb table
    prep_all<<<3072, 256, 0, stream>>>(wq, wv, wc, mem, wgt, bsa, wt,
                                       have_ksm ? ksm : nullptr,
                                       have_wb ? wb : nullptr, kvw);

    dim3 grid_a(NCHUNK_A, BB);
    pass_a<<<grid_a, 512, 0, stream>>>(x, wt + 4096, bv, mem,
                                       have_ksm ? ksm : nullptr, kvw);
    dim3 grid_b(NCHUNK_B / 2, BB);
    pass_b<<<grid_b, 256, 0, stream>>>(x, wt, wt + 4096, wt + 8192,
                                       bq, bv, bc, kvw, wgt, bsa,
                                       have_wb ? wb : nullptr, outp, 0);
    pass_b<<<grid_b, 256, 0, stream>>>(x, wt, wt + 4096, wt + 8192,
                                       bq, bv, bc, kvw, wgt, bsa,
                                       have_wb ? wb : nullptr, outp, NCHUNK_B / 2);
}

// Round 16
// 1581.938 us; speedup vs baseline: 5.0579x; 5.0579x over previous
//
#include <hip/hip_runtime.h>
#include <math.h>
#include <stdint.h>

#define BB 32
#define DD 64
#define HH 8
#define NNN 4096
#define LL 12
#define PP (NNN * LL)            // 49152 positions per (b, channel)

// pass_a geometry (R10 form): 512-thread blocks, 64-pos tiles
#define NTILES_A 24
#define CHUNK_A (64 * NTILES_A)  // 1536
#define NCHUNK_A (PP / CHUNK_A)  // 32  -> 1024 blocks

// pass_b geometry (R8 exact), split into 2 half-grid dispatches
#define NTILES_B 12
#define CHUNK_B (64 * NTILES_B)  // 768
#define NCHUNK_B (PP / CHUNK_B)  // 64 chunks total; 32 per dispatch

#define VSTRIDE 68               // pass_a v_tile row stride (16B-aligned)
#define SCALE 0.35355339059327373f

typedef const __attribute__((address_space(1))) uint32_t gu32;
typedef __attribute__((address_space(3))) uint32_t lu32;

// global->LDS DMA, 16B per lane, zero VGPR cost.
__device__ __forceinline__ void dma16(const float* src, float* dst) {
    __builtin_amdgcn_global_load_lds((gu32*)src, (lu32*)dst, 16, 0, 0);
}

// ---------------------------------------------------------------------------
// prep: transpose the three 64x64 weight matrices into [c][o] layout in ws.
// ---------------------------------------------------------------------------
__global__ void prep(const float* __restrict__ wq, const float* __restrict__ wv,
                     const float* __restrict__ wc, float* __restrict__ wt)
{
    const int i = blockIdx.x * 256 + threadIdx.x;  // i = o*64 + c
    const int o = i >> 6, c = i & 63;
    wt[c * 64 + o]        = wq[i];
    wt[4096 + c * 64 + o] = wv[i];
    wt[8192 + c * 64 + o] = wc[i];
}

// ---------------------------------------------------------------------------
// prep_ksm: key-softmax depends only on (h,l,n); compute once, store p-major:
//   ksm[p][h][x], p = n*12 + l
// ---------------------------------------------------------------------------
__global__ void prep_ksm(const float* __restrict__ mem, float* __restrict__ ksm)
{
    const int g = blockIdx.x * 256 + threadIdx.x;  // (p,h) job
    const int p = g >> 3, h = g & 7;
    const int n = p / 12, l = p - n * 12;
    const float4* mp = (const float4*)(mem + (((size_t)(h * 12 + l) * NNN + n) << 3));
    float4 a0 = mp[0], a1 = mp[1];
    float v0 = a0.x * SCALE, v1 = a0.y * SCALE, v2 = a0.z * SCALE, v3 = a0.w * SCALE;
    float v4 = a1.x * SCALE, v5 = a1.y * SCALE, v6 = a1.z * SCALE, v7 = a1.w * SCALE;
    float m = fmaxf(fmaxf(fmaxf(v0, v1), fmaxf(v2, v3)),
                    fmaxf(fmaxf(v4, v5), fmaxf(v6, v7)));
    float e0 = __expf(v0 - m), e1 = __expf(v1 - m), e2 = __expf(v2 - m), e3 = __expf(v3 - m);
    float e4 = __expf(v4 - m), e5 = __expf(v5 - m), e6 = __expf(v6 - m), e7 = __expf(v7 - m);
    float inv = 1.0f / (e0 + e1 + e2 + e3 + e4 + e5 + e6 + e7);
    float4* op = (float4*)(ksm + ((size_t)g << 3));
    op[0] = make_float4(e0 * inv, e1 * inv, e2 * inv, e3 * inv);
    op[1] = make_float4(e4 * inv, e5 * inv, e6 * inv, e7 * inv);
}

// ---------------------------------------------------------------------------
// prep_wb: fuse epilogue coefficients: wb[i] = { wgt[i]+1, bsa[i] }.
// ---------------------------------------------------------------------------
__global__ void prep_wb(const float* __restrict__ wgt, const float* __restrict__ bsa,
                        float* __restrict__ wb)
{
    const size_t i = (size_t)blockIdx.x * 256 + threadIdx.x;
    wb[i * 2]     = wgt[i] + 1.0f;
    wb[i * 2 + 1] = bsa[i];
}

// ---------------------------------------------------------------------------
// Pass A: R10's measured-best form, verbatim.  (512,4) = 64-VGPR budget
// (no spill), x double-buffered via DMA, ksl single-buffered DMA issued
// after its readers, v_tile slot-swizzled, scalar biases.
// ---------------------------------------------------------------------------
__global__ __launch_bounds__(512, 4)
void pass_a(const float* __restrict__ x, const float* __restrict__ wvt,
            const float* __restrict__ bv, const float* __restrict__ mem,
            const float* __restrict__ ksm,  // p-major key-softmax, or null
            float* __restrict__ kv)
{
    __shared__ float xb0[64 * 64];          // linear (DMA target)
    __shared__ float xb1[64 * 64];          // linear (DMA target)
    __shared__ float ksl[64 * 64];          // linear [pos][h*8+x]
    __shared__ float v_tile[64 * VSTRIDE];  // [p][slot], slot swizzled

    const int t = threadIdx.x;
    const int b = blockIdx.y;
    const int chunk0 = blockIdx.x * CHUNK_A;

    const int p1 = t & 63;
    const int og = t >> 6;           // wave-uniform
    const int o0 = og << 3;
    const int o0u = __builtin_amdgcn_readfirstlane(o0);
    const float* __restrict__ wvu = wvt + o0u;

    float bvl[8];
#pragma unroll
    for (int j = 0; j < 8; j++) bvl[j] = bv[o0u + j];  // scalar path

    // DMA lane mapping
    const int wid = t >> 6;          // wave id 0..7
    const int ln  = t & 63;
    const int g_r = ln >> 4;
    const int g_c4 = (ln & 15) << 2;

    // stage-2 mapping
    const int h2 = (t >> 3) & 7;
    const int x2 = t & 7;
    const int l0 = t >> 6;
    const int l1 = 8 + (t >> 6);
    const bool has2 = (t < 256);

    float acc[2][8];
#pragma unroll
    for (int q = 0; q < 2; q++)
#pragma unroll
        for (int y = 0; y < 8; y++) acc[q][y] = 0.f;

    const float* xb = x + (size_t)(b * 64) * PP;

    auto issue_x = [&](float* dst, int pn) {
        const int r0 = wid << 3;
        dma16(xb + (size_t)(r0 + g_r) * PP + pn + g_c4, dst + (r0 << 6));
        dma16(xb + (size_t)(r0 + 4 + g_r) * PP + pn + g_c4, dst + ((r0 + 4) << 6));
    };
    auto issue_ks = [&](int pn) {
        const int fo = wid << 9;
        const float* s0 = ksm + (((size_t)pn) << 6) + fo + (ln << 2);
        dma16(s0, ksl + fo);
        dma16(s0 + 256, ksl + fo + 256);
    };
    auto fallback_ks = [&](int pbase) {
        int pos = t >> 3, h = t & 7;
        int pg = pbase + pos;
        int n = pg / 12;
        int l = pg - n * 12;
        const float4* mp = (const float4*)(mem + (((size_t)(h * 12 + l) * NNN + n) << 3));
        float4 a0 = mp[0], a1 = mp[1];
        float v0 = a0.x * SCALE, v1 = a0.y * SCALE, v2 = a0.z * SCALE, v3 = a0.w * SCALE;
        float v4 = a1.x * SCALE, v5 = a1.y * SCALE, v6 = a1.z * SCALE, v7 = a1.w * SCALE;
        float m = fmaxf(fmaxf(fmaxf(v0, v1), fmaxf(v2, v3)),
                        fmaxf(fmaxf(v4, v5), fmaxf(v6, v7)));
        float e0 = __expf(v0 - m), e1 = __expf(v1 - m), e2 = __expf(v2 - m), e3 = __expf(v3 - m);
        float e4 = __expf(v4 - m), e5 = __expf(v5 - m), e6 = __expf(v6 - m), e7 = __expf(v7 - m);
        float inv = 1.0f / (e0 + e1 + e2 + e3 + e4 + e5 + e6 + e7);
        float4* kp = (float4*)(ksl + (pos << 6) + (h << 3));
        kp[0] = make_float4(e0 * inv, e1 * inv, e2 * inv, e3 * inv);
        kp[1] = make_float4(e4 * inv, e5 * inv, e6 * inv, e7 * inv);
    };

    issue_x(xb0, chunk0);
    if (ksm) issue_ks(chunk0); else fallback_ks(chunk0);
    __syncthreads();

    for (int tile = 0; tile < NTILES_A; tile++) {
        const int pbase = chunk0 + tile * 64;
        float* bufA = (tile & 1) ? xb1 : xb0;
        float* bufB = (tile & 1) ? xb0 : xb1;
        const bool more = (tile + 1) < NTILES_A;

        if (more) issue_x(bufB, pbase + 64);

        float va[8];
#pragma unroll
        for (int j = 0; j < 8; j++) va[j] = 0.f;
        for (int c = 0; c < 64; c += 4) {
            float xs0 = bufA[(c << 6) + p1];
            float xs1 = bufA[((c + 1) << 6) + p1];
            float xs2 = bufA[((c + 2) << 6) + p1];
            float xs3 = bufA[((c + 3) << 6) + p1];
            const float* w0 = wvu + c * 64;
#pragma unroll
            for (int j = 0; j < 8; j++) {
                va[j] += w0[j] * xs0;
                va[j] += w0[64 + j] * xs1;
                va[j] += w0[128 + j] * xs2;
                va[j] += w0[192 + j] * xs3;
            }
        }
        {
            const int slot = ((og ^ (p1 >> 3)) & 7) << 3;
            float4* vt4 = (float4*)(v_tile + p1 * VSTRIDE + slot);
            float4 w;
            w.x = fmaxf(va[0] + bvl[0], 0.f);
            w.y = fmaxf(va[1] + bvl[1], 0.f);
            w.z = fmaxf(va[2] + bvl[2], 0.f);
            w.w = fmaxf(va[3] + bvl[3], 0.f);
            vt4[0] = w;
            w.x = fmaxf(va[4] + bvl[4], 0.f);
            w.y = fmaxf(va[5] + bvl[5], 0.f);
            w.z = fmaxf(va[6] + bvl[6], 0.f);
            w.w = fmaxf(va[7] + bvl[7], 0.f);
            vt4[1] = w;
        }
        __syncthreads();  // A

        const int r = pbase % 12;
        {
            int s = l0 - r;
            if (s < 0) s += 12;
            for (int p = s; p < 64; p += 12) {
                float ksv = ksl[(p << 6) + (h2 << 3) + x2];
                const int slot = ((h2 ^ (p >> 3)) & 7) << 3;
                const float4* vp = (const float4*)(v_tile + p * VSTRIDE + slot);
                float4 u0 = vp[0], u1 = vp[1];
                acc[0][0] += ksv * u0.x; acc[0][1] += ksv * u0.y;
                acc[0][2] += ksv * u0.z; acc[0][3] += ksv * u0.w;
                acc[0][4] += ksv * u1.x; acc[0][5] += ksv * u1.y;
                acc[0][6] += ksv * u1.z; acc[0][7] += ksv * u1.w;
            }
        }
        if (has2) {
            int s = l1 - r;
            if (s < 0) s += 12;
            for (int p = s; p < 64; p += 12) {
                float ksv = ksl[(p << 6) + (h2 << 3) + x2];
                const int slot = ((h2 ^ (p >> 3)) & 7) << 3;
                const float4* vp = (const float4*)(v_tile + p * VSTRIDE + slot);
                float4 u0 = vp[0], u1 = vp[1];
                acc[1][0] += ksv * u0.x; acc[1][1] += ksv * u0.y;
                acc[1][2] += ksv * u0.z; acc[1][3] += ksv * u0.w;
                acc[1][4] += ksv * u1.x; acc[1][5] += ksv * u1.y;
                acc[1][6] += ksv * u1.z; acc[1][7] += ksv * u1.w;
            }
        }
        __syncthreads();  // B

        if (more) { if (ksm) issue_ks(pbase + 64); else fallback_ks(pbase + 64); }
    }

    {
        float* kvp = kv + (((size_t)((b * 12 + l0) * 8 + h2)) << 6) + (x2 << 3);
#pragma unroll
        for (int y = 0; y < 8; y++) atomicAdd(kvp + y, acc[0][y]);
    }
    if (has2) {
        float* kvp = kv + (((size_t)((b * 12 + l1) * 8 + h2)) << 6) + (x2 << 3);
#pragma unroll
        for (int y = 0; y < 8; y++) atomicAdd(kvp + y, acc[1][y]);
    }
}

// ---------------------------------------------------------------------------
// Pass B: R8 EXACT compute (measured best, 392 us/half in R14).  256t,
// 16 outputs/thread, direct strided global x with COMPILER-scheduled loads
// (R15 proved manual 2-deep pipelining regresses 9.4x -- the compiler's
// clause batching at (256,4) beats any source-level reordering), scalar
// weights, kv slice in swizzled LDS, fused wb epilogue.
// ---------------------------------------------------------------------------
__global__ __launch_bounds__(256, 4)
void pass_b(const float* __restrict__ x, const float* __restrict__ wqt,
            const float* __restrict__ wvt, const float* __restrict__ wct,
            const float* __restrict__ bq, const float* __restrict__ bv,
            const float* __restrict__ bc, const float* __restrict__ kv,
            const float* __restrict__ wgt, const float* __restrict__ bsa,
            const float* __restrict__ wb,   // fused pairs, or null
            float* __restrict__ out, int chunk_base)
{
    __shared__ float kv_lds[12 * 512];  // [l][h][x^(l&3)][y], 24 KB
    __shared__ float y_tile[64 * 64];   // [c][p], 16 KB

    const int t = threadIdx.x;
    const int b = blockIdx.y;
    const int chunk0 = (chunk_base + blockIdx.x) * CHUNK_B;

    const int p1 = t & 63;
    const int og = t >> 6;
    const int o0 = og << 4;
    const int o0u = __builtin_amdgcn_readfirstlane(o0);
    const float* __restrict__ wqu = wqt + o0u;
    const float* __restrict__ wvu = wvt + o0u;
    const float* __restrict__ wcu = wct + o0u;

    // stage this batch's kv slice once, bank-swizzled
    {
        const float* kvb = kv + (size_t)b * 6144;
        for (int i = t; i < 6144; i += 256) {
            const int l = i >> 9;
            const int h = (i >> 6) & 7;
            const int xx = (i >> 3) & 7;
            const int y = i & 7;
            kv_lds[(l << 9) + (h << 6) + ((xx ^ (l & 3)) << 3) + y] = kvb[i];
        }
    }

    float bql[16], bvl[16], bcl[16];
#pragma unroll
    for (int j = 0; j < 16; j++) {
        bql[j] = bq[o0 + j];
        bvl[j] = bv[o0 + j];
        bcl[j] = bc[o0 + j];
    }

    const float* xb = x + (size_t)(b * 64) * PP;
    float* ob = out + (size_t)(b * 64) * PP;

    __syncthreads();

    for (int tile_i = 0; tile_i < NTILES_B; tile_i++) {
        const int pbase = chunk0 + tile_i * 64;
        const int pg = pbase + p1;
        const int l = pg % 12;

        // ---- q and v convs (direct strided global x + scalar weights)
        float qa[16], va[16];
#pragma unroll
        for (int j = 0; j < 16; j++) { qa[j] = 0.f; va[j] = 0.f; }
        const float* xp = xb + pg;
        for (int c = 0; c < 64; c += 4) {
            float xs0 = xp[(size_t)c * PP];
            float xs1 = xp[(size_t)(c + 1) * PP];
            float xs2 = xp[(size_t)(c + 2) * PP];
            float xs3 = xp[(size_t)(c + 3) * PP];
            const float* q0 = wqu + c * 64;
            const float* v0 = wvu + c * 64;
#pragma unroll
            for (int j = 0; j < 16; j++) {
                qa[j] += q0[j] * xs0;       va[j] += v0[j] * xs0;
                qa[j] += q0[64 + j] * xs1;  va[j] += v0[64 + j] * xs1;
                qa[j] += q0[128 + j] * xs2; va[j] += v0[128 + j] * xs2;
                qa[j] += q0[192 + j] * xs3; va[j] += v0[192 + j] * xs3;
            }
        }
#pragma unroll
        for (int j = 0; j < 16; j++) {
            qa[j] = fmaxf(qa[j] + bql[j], 0.f) * SCALE;
            va[j] = fmaxf(va[j] + bvl[j], 0.f);
        }

        // ---- softmax over DK=8 per head (2 heads/thread, in-register)
#pragma unroll
        for (int hh = 0; hh < 2; hh++) {
            float* qh = qa + hh * 8;
            float m = fmaxf(fmaxf(fmaxf(qh[0], qh[1]), fmaxf(qh[2], qh[3])),
                            fmaxf(fmaxf(qh[4], qh[5]), fmaxf(qh[6], qh[7])));
            float s = 0.f;
#pragma unroll
            for (int xk = 0; xk < 8; xk++) { qh[xk] = __expf(qh[xk] - m); s += qh[xk]; }
            float inv = 1.0f / s;
#pragma unroll
            for (int xk = 0; xk < 8; xk++) qh[xk] *= inv;
        }

        // ---- attn: y = q_sm @ kv + v   (kv from swizzled LDS)
        const int lsw = l & 3;
#pragma unroll
        for (int hh = 0; hh < 2; hh++) {
            const int h = og * 2 + hh;
            const float* kvp = kv_lds + (l << 9) + (h << 6);
            float yv[8];
#pragma unroll
            for (int y = 0; y < 8; y++) yv[y] = va[hh * 8 + y];
#pragma unroll
            for (int xk = 0; xk < 8; xk++) {
                float qv = qa[hh * 8 + xk];
                const float4* kp = (const float4*)(kvp + ((xk ^ lsw) << 3));
                float4 k0 = kp[0], k1 = kp[1];
                yv[0] += qv * k0.x; yv[1] += qv * k0.y;
                yv[2] += qv * k0.z; yv[3] += qv * k0.w;
                yv[4] += qv * k1.x; yv[5] += qv * k1.y;
                yv[6] += qv * k1.z; yv[7] += qv * k1.w;
            }
#pragma unroll
            for (int y = 0; y < 8; y++)
                y_tile[((o0 + hh * 8 + y) << 6) + p1] = yv[y];
        }
        __syncthreads();

        // ---- output conv + epilogue
        float ca[16];
#pragma unroll
        for (int j = 0; j < 16; j++) ca[j] = 0.f;
        for (int c = 0; c < 64; c += 4) {
            float y0 = y_tile[(c << 6) + p1];
            float y1 = y_tile[((c + 1) << 6) + p1];
            float y2 = y_tile[((c + 2) << 6) + p1];
            float y3 = y_tile[((c + 3) << 6) + p1];
            const float* w0 = wcu + c * 64;
#pragma unroll
            for (int j = 0; j < 16; j++) {
                ca[j] += w0[j] * y0;
                ca[j] += w0[64 + j] * y1;
                ca[j] += w0[128 + j] * y2;
                ca[j] += w0[192 + j] * y3;
            }
        }
        if (wb) {
#pragma unroll
            for (int j = 0; j < 16; j++) {
                float yc = fmaxf(ca[j] + bcl[j], 0.f);
                size_t oi = (size_t)(o0 + j) * PP + pg;
                float2 w2 = *(const float2*)(wb + oi * 2);
                ob[oi] = yc * w2.x + w2.y;
            }
        } else {
#pragma unroll
            for (int j = 0; j < 16; j++) {
                float yc = fmaxf(ca[j] + bcl[j], 0.f);
                size_t oi = (size_t)(o0 + j) * PP + pg;
                ob[oi] = yc * (wgt[oi] + 1.0f) + bsa[oi];
            }
        }
        __syncthreads();  // y reads done before next tile's y writes
    }
}

extern "C" void kernel_launch(void* const* d_in, const int* in_sizes, int n_in,
                              void* d_out, int out_size, void* d_ws, size_t ws_size,
                              hipStream_t stream) {
    const float* x   = (const float*)d_in[0];
    const float* wq  = (const float*)d_in[1];
    const float* bq  = (const float*)d_in[2];
    const float* wv  = (const float*)d_in[3];
    const float* bv  = (const float*)d_in[4];
    const float* wc  = (const float*)d_in[5];
    const float* bc  = (const float*)d_in[6];
    const float* mem = (const float*)d_in[7];
    const float* wgt = (const float*)d_in[8];
    const float* bsa = (const float*)d_in[9];
    // d_in[10], d_in[11] (nv1, nv2) are mathematically dead:
    // row-sums of a softmax over its own axis are exactly 1 -> attn_dyn = v5.
    float* outp = (float*)d_out;

    const size_t kv_floats  = (size_t)BB * LL * HH * 64;   // 196608
    const size_t wt_floats  = 3 * 4096;                    // 12288
    const size_t ksm_floats = (size_t)PP * 64;             // 3145728 (12.6 MB)
    const size_t wb_floats  = (size_t)PP * 64 * 2;         // 6291456 (25.2 MB)

    float* kvw = (float*)d_ws;
    float* wt  = kvw + kv_floats;
    float* ksm = wt + wt_floats;
    float* wb  = ksm + ksm_floats;
    const bool have_ksm =
        ws_size >= (kv_floats + wt_floats + ksm_floats) * sizeof(float);
    const bool have_wb =
        ws_size >= (kv_floats + wt_floats + ksm_floats + wb_floats) * sizeof(float);

    hipMemsetAsync(kvw, 0, kv_floats * sizeof(float), stream);

    prep<<<16, 256, 0, stream>>>(wq, wv, wc, wt);
    if (have_ksm) {
        prep_ksm<<<(PP * 8) / 256, 256, 0, stream>>>(mem, ksm);
    }
    if (have_wb) {
        prep_wb<<<(PP * 64) / 256, 256, 0, stream>>>(wgt, bsa, wb);
    }

    dim3 grid_a(NCHUNK_A, BB);
    pass_a<<<grid_a, 512, 0, stream>>>(x, wt + 4096, bv, mem,
                                       have_ksm ? ksm : nullptr, kvw);
    dim3 grid_b(NCHUNK_B / 2, BB);
    pass_b<<<grid_b, 256, 0, stream>>>(x, wt, wt + 4096, wt + 8192,
                                       bq, bv, bc, kvw, wgt, bsa,
                                       have_wb ? wb : nullptr, outp, 0);
    pass_b<<<grid_b, 256, 0, stream>>>(x, wt, wt + 4096, wt + 8192,
                                       bq, bv, bc, kvw, wgt, bsa,
                                       have_wb ? wb : nullptr, outp, NCHUNK_B / 2);
}

// Round 17
// 1577.822 us; speedup vs baseline: 5.0711x; 1.0026x over previous
//
#include <hip/hip_runtime.h>
#include <math.h>
#include <stdint.h>

#define BB 32
#define DD 64
#define HH 8
#define NNN 4096
#define LL 12
#define PP (NNN * LL)            // 49152 positions per (b, channel)

// pass_a geometry (R10 form): 512-thread blocks, 64-pos tiles
#define NTILES_A 24
#define CHUNK_A (64 * NTILES_A)  // 1536
#define NCHUNK_A (PP / CHUNK_A)  // 32  -> 1024 blocks

// pass_b geometry (R8 exact), split into 2 half-grid dispatches
#define NTILES_B 12
#define CHUNK_B (64 * NTILES_B)  // 768
#define NCHUNK_B (PP / CHUNK_B)  // 64 chunks total; 32 per dispatch

#define VSTRIDE 68               // pass_a v_tile row stride (16B-aligned)
#define SCALE 0.35355339059327373f

typedef const __attribute__((address_space(1))) uint32_t gu32;
typedef __attribute__((address_space(3))) uint32_t lu32;

// global->LDS DMA, 16B per lane, zero VGPR cost.
__device__ __forceinline__ void dma16(const float* src, float* dst) {
    __builtin_amdgcn_global_load_lds((gu32*)src, (lu32*)dst, 16, 0, 0);
}

// ---------------------------------------------------------------------------
// prep_all: fused {kv zero, weight transpose, key-softmax table, wb table}.
// One 3072x256 launch replaces memset + 3 prep kernels (correctness proven
// in R15; that round's regression was isolated to pass_b by the counters).
// ---------------------------------------------------------------------------
__global__ void prep_all(const float* __restrict__ wq, const float* __restrict__ wv,
                         const float* __restrict__ wc, const float* __restrict__ mem,
                         const float* __restrict__ wgt, const float* __restrict__ bsa,
                         float* __restrict__ wt, float* __restrict__ ksm,
                         float* __restrict__ wb, float* __restrict__ kvz)
{
    const int t = blockIdx.x * 256 + threadIdx.x;  // 0..786431

    // kv zero: 196608 floats = 49152 float4
    if (t < 49152) ((float4*)kvz)[t] = make_float4(0.f, 0.f, 0.f, 0.f);

    // weight transpose: 4096 jobs (i = o*64 + c)
    if (t < 4096) {
        const int o = t >> 6, c = t & 63;
        wt[c * 64 + o]        = wq[t];
        wt[4096 + c * 64 + o] = wv[t];
        wt[8192 + c * 64 + o] = wc[t];
    }

    // key-softmax table: 393216 (p,h) jobs; ksm[p][h][x], p = n*12+l
    if (ksm && t < 393216) {
        const int p = t >> 3, h = t & 7;
        const int n = p / 12, l = p - n * 12;
        const float4* mp = (const float4*)(mem + (((size_t)(h * 12 + l) * NNN + n) << 3));
        float4 a0 = mp[0], a1 = mp[1];
        float v0 = a0.x * SCALE, v1 = a0.y * SCALE, v2 = a0.z * SCALE, v3 = a0.w * SCALE;
        float v4 = a1.x * SCALE, v5 = a1.y * SCALE, v6 = a1.z * SCALE, v7 = a1.w * SCALE;
        float m = fmaxf(fmaxf(fmaxf(v0, v1), fmaxf(v2, v3)),
                        fmaxf(fmaxf(v4, v5), fmaxf(v6, v7)));
        float e0 = __expf(v0 - m), e1 = __expf(v1 - m), e2 = __expf(v2 - m), e3 = __expf(v3 - m);
        float e4 = __expf(v4 - m), e5 = __expf(v5 - m), e6 = __expf(v6 - m), e7 = __expf(v7 - m);
        float inv = 1.0f / (e0 + e1 + e2 + e3 + e4 + e5 + e6 + e7);
        float4* op = (float4*)(ksm + ((size_t)t << 3));
        op[0] = make_float4(e0 * inv, e1 * inv, e2 * inv, e3 * inv);
        op[1] = make_float4(e4 * inv, e5 * inv, e6 * inv, e7 * inv);
    }

    // wb table: 3145728 pair-entries, 4 per thread, float4 in/out
    if (wb) {
        const size_t i0 = (size_t)t << 2;
        float4 wg = *(const float4*)(wgt + i0);
        float4 bs = *(const float4*)(bsa + i0);
        float4* op = (float4*)(wb + (i0 << 1));
        op[0] = make_float4(wg.x + 1.f, bs.x, wg.y + 1.f, bs.y);
        op[1] = make_float4(wg.z + 1.f, bs.z, wg.w + 1.f, bs.w);
    }
}

// ---------------------------------------------------------------------------
// Pass A: R10's measured-best form, verbatim.  (512,4) = 64-VGPR budget
// (no spill), x double-buffered via DMA, ksl single-buffered DMA issued
// after its readers, v_tile slot-swizzled, scalar biases.
// ---------------------------------------------------------------------------
__global__ __launch_bounds__(512, 4)
void pass_a(const float* __restrict__ x, const float* __restrict__ wvt,
            const float* __restrict__ bv, const float* __restrict__ mem,
            const float* __restrict__ ksm,  // p-major key-softmax, or null
            float* __restrict__ kv)
{
    __shared__ float xb0[64 * 64];          // linear (DMA target)
    __shared__ float xb1[64 * 64];          // linear (DMA target)
    __shared__ float ksl[64 * 64];          // linear [pos][h*8+x]
    __shared__ float v_tile[64 * VSTRIDE];  // [p][slot], slot swizzled

    const int t = threadIdx.x;
    const int b = blockIdx.y;
    const int chunk0 = blockIdx.x * CHUNK_A;

    const int p1 = t & 63;
    const int og = t >> 6;           // wave-uniform
    const int o0 = og << 3;
    const int o0u = __builtin_amdgcn_readfirstlane(o0);
    const float* __restrict__ wvu = wvt + o0u;

    float bvl[8];
#pragma unroll
    for (int j = 0; j < 8; j++) bvl[j] = bv[o0u + j];  // scalar path

    // DMA lane mapping
    const int wid = t >> 6;          // wave id 0..7
    const int ln  = t & 63;
    const int g_r = ln >> 4;
    const int g_c4 = (ln & 15) << 2;

    // stage-2 mapping
    const int h2 = (t >> 3) & 7;
    const int x2 = t & 7;
    const int l0 = t >> 6;
    const int l1 = 8 + (t >> 6);
    const bool has2 = (t < 256);

    float acc[2][8];
#pragma unroll
    for (int q = 0; q < 2; q++)
#pragma unroll
        for (int y = 0; y < 8; y++) acc[q][y] = 0.f;

    const float* xb = x + (size_t)(b * 64) * PP;

    auto issue_x = [&](float* dst, int pn) {
        const int r0 = wid << 3;
        dma16(xb + (size_t)(r0 + g_r) * PP + pn + g_c4, dst + (r0 << 6));
        dma16(xb + (size_t)(r0 + 4 + g_r) * PP + pn + g_c4, dst + ((r0 + 4) << 6));
    };
    auto issue_ks = [&](int pn) {
        const int fo = wid << 9;
        const float* s0 = ksm + (((size_t)pn) << 6) + fo + (ln << 2);
        dma16(s0, ksl + fo);
        dma16(s0 + 256, ksl + fo + 256);
    };
    auto fallback_ks = [&](int pbase) {
        int pos = t >> 3, h = t & 7;
        int pg = pbase + pos;
        int n = pg / 12;
        int l = pg - n * 12;
        const float4* mp = (const float4*)(mem + (((size_t)(h * 12 + l) * NNN + n) << 3));
        float4 a0 = mp[0], a1 = mp[1];
        float v0 = a0.x * SCALE, v1 = a0.y * SCALE, v2 = a0.z * SCALE, v3 = a0.w * SCALE;
        float v4 = a1.x * SCALE, v5 = a1.y * SCALE, v6 = a1.z * SCALE, v7 = a1.w * SCALE;
        float m = fmaxf(fmaxf(fmaxf(v0, v1), fmaxf(v2, v3)),
                        fmaxf(fmaxf(v4, v5), fmaxf(v6, v7)));
        float e0 = __expf(v0 - m), e1 = __expf(v1 - m), e2 = __expf(v2 - m), e3 = __expf(v3 - m);
        float e4 = __expf(v4 - m), e5 = __expf(v5 - m), e6 = __expf(v6 - m), e7 = __expf(v7 - m);
        float inv = 1.0f / (e0 + e1 + e2 + e3 + e4 + e5 + e6 + e7);
        float4* kp = (float4*)(ksl + (pos << 6) + (h << 3));
        kp[0] = make_float4(e0 * inv, e1 * inv, e2 * inv, e3 * inv);
        kp[1] = make_float4(e4 * inv, e5 * inv, e6 * inv, e7 * inv);
    };

    issue_x(xb0, chunk0);
    if (ksm) issue_ks(chunk0); else fallback_ks(chunk0);
    __syncthreads();

    for (int tile = 0; tile < NTILES_A; tile++) {
        const int pbase = chunk0 + tile * 64;
        float* bufA = (tile & 1) ? xb1 : xb0;
        float* bufB = (tile & 1) ? xb0 : xb1;
        const bool more = (tile + 1) < NTILES_A;

        if (more) issue_x(bufB, pbase + 64);

        float va[8];
#pragma unroll
        for (int j = 0; j < 8; j++) va[j] = 0.f;
        for (int c = 0; c < 64; c += 4) {
            float xs0 = bufA[(c << 6) + p1];
            float xs1 = bufA[((c + 1) << 6) + p1];
            float xs2 = bufA[((c + 2) << 6) + p1];
            float xs3 = bufA[((c + 3) << 6) + p1];
            const float* w0 = wvu + c * 64;
#pragma unroll
            for (int j = 0; j < 8; j++) {
                va[j] += w0[j] * xs0;
                va[j] += w0[64 + j] * xs1;
                va[j] += w0[128 + j] * xs2;
                va[j] += w0[192 + j] * xs3;
            }
        }
        {
            const int slot = ((og ^ (p1 >> 3)) & 7) << 3;
            float4* vt4 = (float4*)(v_tile + p1 * VSTRIDE + slot);
            float4 w;
            w.x = fmaxf(va[0] + bvl[0], 0.f);
            w.y = fmaxf(va[1] + bvl[1], 0.f);
            w.z = fmaxf(va[2] + bvl[2], 0.f);
            w.w = fmaxf(va[3] + bvl[3], 0.f);
            vt4[0] = w;
            w.x = fmaxf(va[4] + bvl[4], 0.f);
            w.y = fmaxf(va[5] + bvl[5], 0.f);
            w.z = fmaxf(va[6] + bvl[6], 0.f);
            w.w = fmaxf(va[7] + bvl[7], 0.f);
            vt4[1] = w;
        }
        __syncthreads();  // A

        const int r = pbase % 12;
        {
            int s = l0 - r;
            if (s < 0) s += 12;
            for (int p = s; p < 64; p += 12) {
                float ksv = ksl[(p << 6) + (h2 << 3) + x2];
                const int slot = ((h2 ^ (p >> 3)) & 7) << 3;
                const float4* vp = (const float4*)(v_tile + p * VSTRIDE + slot);
                float4 u0 = vp[0], u1 = vp[1];
                acc[0][0] += ksv * u0.x; acc[0][1] += ksv * u0.y;
                acc[0][2] += ksv * u0.z; acc[0][3] += ksv * u0.w;
                acc[0][4] += ksv * u1.x; acc[0][5] += ksv * u1.y;
                acc[0][6] += ksv * u1.z; acc[0][7] += ksv * u1.w;
            }
        }
        if (has2) {
            int s = l1 - r;
            if (s < 0) s += 12;
            for (int p = s; p < 64; p += 12) {
                float ksv = ksl[(p << 6) + (h2 << 3) + x2];
                const int slot = ((h2 ^ (p >> 3)) & 7) << 3;
                const float4* vp = (const float4*)(v_tile + p * VSTRIDE + slot);
                float4 u0 = vp[0], u1 = vp[1];
                acc[1][0] += ksv * u0.x; acc[1][1] += ksv * u0.y;
                acc[1][2] += ksv * u0.z; acc[1][3] += ksv * u0.w;
                acc[1][4] += ksv * u1.x; acc[1][5] += ksv * u1.y;
                acc[1][6] += ksv * u1.z; acc[1][7] += ksv * u1.w;
            }
        }
        __syncthreads();  // B

        if (more) { if (ksm) issue_ks(pbase + 64); else fallback_ks(pbase + 64); }
    }

    {
        float* kvp = kv + (((size_t)((b * 12 + l0) * 8 + h2)) << 6) + (x2 << 3);
#pragma unroll
        for (int y = 0; y < 8; y++) atomicAdd(kvp + y, acc[0][y]);
    }
    if (has2) {
        float* kvp = kv + (((size_t)((b * 12 + l1) * 8 + h2)) << 6) + (x2 << 3);
#pragma unroll
        for (int y = 0; y < 8; y++) atomicAdd(kvp + y, acc[1][y]);
    }
}

// ---------------------------------------------------------------------------
// Pass B: R8 EXACT compute (measured best, ~400 us/half).  256t, 16
// outputs/thread, direct strided global x with COMPILER-scheduled loads
// (R15 proved manual pipelining regresses 9.4x), scalar weights, kv slice
// in swizzled LDS, fused wb epilogue, (256,4) = the only non-spilling bound.
// ---------------------------------------------------------------------------
__global__ __launch_bounds__(256, 4)
void pass_b(const float* __restrict__ x, const float* __restrict__ wqt,
            const float* __restrict__ wvt, const float* __restrict__ wct,
            const float* __restrict__ bq, const float* __restrict__ bv,
            const float* __restrict__ bc, const float* __restrict__ kv,
            const float* __restrict__ wgt, const float* __restrict__ bsa,
            const float* __restrict__ wb,   // fused pairs, or null
            float* __restrict__ out, int chunk_base)
{
    __shared__ float kv_lds[12 * 512];  // [l][h][x^(l&3)][y], 24 KB
    __shared__ float y_tile[64 * 64];   // [c][p], 16 KB

    const int t = threadIdx.x;
    const int b = blockIdx.y;
    const int chunk0 = (chunk_base + blockIdx.x) * CHUNK_B;

    const int p1 = t & 63;
    const int og = t >> 6;
    const int o0 = og << 4;
    const int o0u = __builtin_amdgcn_readfirstlane(o0);
    const float* __restrict__ wqu = wqt + o0u;
    const float* __restrict__ wvu = wvt + o0u;
    const float* __restrict__ wcu = wct + o0u;

    // stage this batch's kv slice once, bank-swizzled
    {
        const float* kvb = kv + (size_t)b * 6144;
        for (int i = t; i < 6144; i += 256) {
            const int l = i >> 9;
            const int h = (i >> 6) & 7;
            const int xx = (i >> 3) & 7;
            const int y = i & 7;
            kv_lds[(l << 9) + (h << 6) + ((xx ^ (l & 3)) << 3) + y] = kvb[i];
        }
    }

    float bql[16], bvl[16], bcl[16];
#pragma unroll
    for (int j = 0; j < 16; j++) {
        bql[j] = bq[o0 + j];
        bvl[j] = bv[o0 + j];
        bcl[j] = bc[o0 + j];
    }

    const float* xb = x + (size_t)(b * 64) * PP;
    float* ob = out + (size_t)(b * 64) * PP;

    __syncthreads();

    for (int tile_i = 0; tile_i < NTILES_B; tile_i++) {
        const int pbase = chunk0 + tile_i * 64;
        const int pg = pbase + p1;
        const int l = pg % 12;

        // ---- q and v convs (direct strided global x + scalar weights)
        float qa[16], va[16];
#pragma unroll
        for (int j = 0; j < 16; j++) { qa[j] = 0.f; va[j] = 0.f; }
        const float* xp = xb + pg;
        for (int c = 0; c < 64; c += 4) {
            float xs0 = xp[(size_t)c * PP];
            float xs1 = xp[(size_t)(c + 1) * PP];
            float xs2 = xp[(size_t)(c + 2) * PP];
            float xs3 = xp[(size_t)(c + 3) * PP];
            const float* q0 = wqu + c * 64;
            const float* v0 = wvu + c * 64;
#pragma unroll
            for (int j = 0; j < 16; j++) {
                qa[j] += q0[j] * xs0;       va[j] += v0[j] * xs0;
                qa[j] += q0[64 + j] * xs1;  va[j] += v0[64 + j] * xs1;
                qa[j] += q0[128 + j] * xs2; va[j] += v0[128 + j] * xs2;
                qa[j] += q0[192 + j] * xs3; va[j] += v0[192 + j] * xs3;
            }
        }
#pragma unroll
        for (int j = 0; j < 16; j++) {
            qa[j] = fmaxf(qa[j] + bql[j], 0.f) * SCALE;
            va[j] = fmaxf(va[j] + bvl[j], 0.f);
        }

        // ---- softmax over DK=8 per head (2 heads/thread, in-register)
#pragma unroll
        for (int hh = 0; hh < 2; hh++) {
            float* qh = qa + hh * 8;
            float m = fmaxf(fmaxf(fmaxf(qh[0], qh[1]), fmaxf(qh[2], qh[3])),
                            fmaxf(fmaxf(qh[4], qh[5]), fmaxf(qh[6], qh[7])));
            float s = 0.f;
#pragma unroll
            for (int xk = 0; xk < 8; xk++) { qh[xk] = __expf(qh[xk] - m); s += qh[xk]; }
            float inv = 1.0f / s;
#pragma unroll
            for (int xk = 0; xk < 8; xk++) qh[xk] *= inv;
        }

        // ---- attn: y = q_sm @ kv + v   (kv from swizzled LDS)
        const int lsw = l & 3;
#pragma unroll
        for (int hh = 0; hh < 2; hh++) {
            const int h = og * 2 + hh;
            const float* kvp = kv_lds + (l << 9) + (h << 6);
            float yv[8];
#pragma unroll
            for (int y = 0; y < 8; y++) yv[y] = va[hh * 8 + y];
#pragma unroll
            for (int xk = 0; xk < 8; xk++) {
                float qv = qa[hh * 8 + xk];
                const float4* kp = (const float4*)(kvp + ((xk ^ lsw) << 3));
                float4 k0 = kp[0], k1 = kp[1];
                yv[0] += qv * k0.x; yv[1] += qv * k0.y;
                yv[2] += qv * k0.z; yv[3] += qv * k0.w;
                yv[4] += qv * k1.x; yv[5] += qv * k1.y;
                yv[6] += qv * k1.z; yv[7] += qv * k1.w;
            }
#pragma unroll
            for (int y = 0; y < 8; y++)
                y_tile[((o0 + hh * 8 + y) << 6) + p1] = yv[y];
        }
        __syncthreads();

        // ---- output conv + epilogue
        float ca[16];
#pragma unroll
        for (int j = 0; j < 16; j++) ca[j] = 0.f;
        for (int c = 0; c < 64; c += 4) {
            float y0 = y_tile[(c << 6) + p1];
            float y1 = y_tile[((c + 1) << 6) + p1];
            float y2 = y_tile[((c + 2) << 6) + p1];
            float y3 = y_tile[((c + 3) << 6) + p1];
            const float* w0 = wcu + c * 64;
#pragma unroll
            for (int j = 0; j < 16; j++) {
                ca[j] += w0[j] * y0;
                ca[j] += w0[64 + j] * y1;
                ca[j] += w0[128 + j] * y2;
                ca[j] += w0[192 + j] * y3;
            }
        }
        if (wb) {
#pragma unroll
            for (int j = 0; j < 16; j++) {
                float yc = fmaxf(ca[j] + bcl[j], 0.f);
                size_t oi = (size_t)(o0 + j) * PP + pg;
                float2 w2 = *(const float2*)(wb + oi * 2);
                ob[oi] = yc * w2.x + w2.y;
            }
        } else {
#pragma unroll
            for (int j = 0; j < 16; j++) {
                float yc = fmaxf(ca[j] + bcl[j], 0.f);
                size_t oi = (size_t)(o0 + j) * PP + pg;
                ob[oi] = yc * (wgt[oi] + 1.0f) + bsa[oi];
            }
        }
        __syncthreads();  // y reads done before next tile's y writes
    }
}

extern "C" void kernel_launch(void* const* d_in, const int* in_sizes, int n_in,
                              void* d_out, int out_size, void* d_ws, size_t ws_size,
                              hipStream_t stream) {
    const float* x   = (const float*)d_in[0];
    const float* wq  = (const float*)d_in[1];
    const float* bq  = (const float*)d_in[2];
    const float* wv  = (const float*)d_in[3];
    const float* bv  = (const float*)d_in[4];
    const float* wc  = (const float*)d_in[5];
    const float* bc  = (const float*)d_in[6];
    const float* mem = (const float*)d_in[7];
    const float* wgt = (const float*)d_in[8];
    const float* bsa = (const float*)d_in[9];
    // d_in[10], d_in[11] (nv1, nv2) are mathematically dead:
    // row-sums of a softmax over its own axis are exactly 1 -> attn_dyn = v5.
    float* outp = (float*)d_out;

    const size_t kv_floats  = (size_t)BB * LL * HH * 64;   // 196608
    const size_t wt_floats  = 3 * 4096;                    // 12288
    const size_t ksm_floats = (size_t)PP * 64;             // 3145728 (12.6 MB)
    const size_t wb_floats  = (size_t)PP * 64 * 2;         // 6291456 (25.2 MB)

    float* kvw = (float*)d_ws;
    float* wt  = kvw + kv_floats;
    float* ksm = wt + wt_floats;
    float* wb  = ksm + ksm_floats;
    const bool have_ksm =
        ws_size >= (kv_floats + wt_floats + ksm_floats) * sizeof(float);
    const bool have_wb =
        ws_size >= (kv_floats + wt_floats + ksm_floats + wb_floats) * sizeof(float);

    // fused prep: kv zero + weight transpose + ksm table + wb table (1 launch)
    prep_all<<<3072, 256, 0, stream>>>(wq, wv, wc, mem, wgt, bsa, wt,
                                       have_ksm ? ksm : nullptr,
                                       have_wb ? wb : nullptr, kvw);

    dim3 grid_a(NCHUNK_A, BB);
    pass_a<<<grid_a, 512, 0, stream>>>(x, wt + 4096, bv, mem,
                                       have_ksm ? ksm : nullptr, kvw);
    dim3 grid_b(NCHUNK_B / 2, BB);
    pass_b<<<grid_b, 256, 0, stream>>>(x, wt, wt + 4096, wt + 8192,
                                       bq, bv, bc, kvw, wgt, bsa,
                                       have_wb ? wb : nullptr, outp, 0);
    pass_b<<<grid_b, 256, 0, stream>>>(x, wt, wt + 4096, wt + 8192,
                                       bq, bv, bc, kvw, wgt, bsa,
                                       have_wb ? wb : nullptr, outp, NCHUNK_B / 2);
}